// Round 10
// baseline (559.494 us; speedup 1.0000x reference)
//
#include <hip/hip_runtime.h>
#include <cstddef>
#include <cstdint>

#define NND 100000
#define NED 1600000
#define NEP (NED + NND)

typedef short v8s __attribute__((ext_vector_type(8)));
typedef float v4f __attribute__((ext_vector_type(4)));

// ---------------- bf16 split helpers ----------------
__device__ __forceinline__ uint32_t f32_to_bf16_rne(float x) {
    uint32_t u = __builtin_bit_cast(uint32_t, x);
    return (u + 0x7fffu + ((u >> 16) & 1u)) >> 16;
}
__device__ __forceinline__ float bf16bits_to_f32(uint32_t b) {
    return __builtin_bit_cast(float, b << 16);
}

// ---------------- edge dtype detection ----------------
__global__ void k_detect(const long long* __restrict__ ei, int* __restrict__ flag) {
    __shared__ int ok;
    if (threadIdx.x == 0) ok = 1;
    __syncthreads();
    for (int i = threadIdx.x; i < 2048; i += blockDim.x) {
        long long v = ei[i];
        if (v < 0 || v >= NND) ok = 0;
    }
    __syncthreads();
    if (threadIdx.x == 0) *flag = ok;
}

__device__ __forceinline__ void load_edge(const void* ei, int is64, int e, int& src, int& dst) {
    if (e >= NED) { src = dst = e - NED; return; }  // self-loop
    if (is64) {
        const long long* p = (const long long*)ei;
        src = (int)p[e];
        dst = (int)p[NED + e];
    } else {
        const int* p = (const int*)ei;
        src = p[e];
        dst = p[NED + e];
    }
}

// ---------------- degree (2 edges/thread) ----------------
__global__ void k_deg(const void* __restrict__ ei, const int* __restrict__ flag,
                      int* __restrict__ deg) {
    int e0 = (blockIdx.x * 256 + threadIdx.x) * 2;
    if (e0 >= NEP) return;
    const int is64 = *flag;
    int s0, d0, s1, d1;
    load_edge(ei, is64, e0, s0, d0);
    load_edge(ei, is64, e0 + 1, s1, d1);
    atomicAdd(&deg[d0], 1);
    atomicAdd(&deg[d1], 1);
}

// ---------------- exclusive scan of deg -> row_off (+ dinv fused) ----------------
__global__ __launch_bounds__(1024) void k_scan1(const int* __restrict__ deg,
                                                int* __restrict__ row_off,
                                                int* __restrict__ bsum,
                                                float* __restrict__ dinv) {
    __shared__ int sh[1024];
    int i = blockIdx.x * 1024 + threadIdx.x;
    int v = (i < NND) ? deg[i] : 0;
    if (i < NND) {
        int d = v < 1 ? 1 : v;
        dinv[i] = 1.0f / sqrtf((float)d);
    }
    sh[threadIdx.x] = v;
    __syncthreads();
    for (int off = 1; off < 1024; off <<= 1) {
        int t = 0;
        if ((int)threadIdx.x >= off) t = sh[threadIdx.x - off];
        __syncthreads();
        sh[threadIdx.x] += t;
        __syncthreads();
    }
    if (i < NND) row_off[i] = sh[threadIdx.x] - v;  // exclusive (within block)
    if (threadIdx.x == 1023) bsum[blockIdx.x] = sh[1023];
}

// ---------------- merged scan2+scan3: add block-prefix of bsum in-block ----------------
// Each block covers 256 indices -> exactly one 1024-bucket (blockIdx>>2).
__global__ void k_scan23(int* __restrict__ row_off, const int* __restrict__ bsum) {
    __shared__ int sh[128];
    const int bucket = blockIdx.x >> 2;
    const int t = threadIdx.x;
    if (t < 128) sh[t] = (t < bucket) ? bsum[t] : 0;  // bucket <= 97 < 128
    __syncthreads();
#pragma unroll
    for (int off = 64; off > 0; off >>= 1) {
        if (t < off) sh[t] += sh[t + off];
        __syncthreads();
    }
    const int pref = sh[0];
    const int i = blockIdx.x * 256 + t;
    if (i < NND) row_off[i] += pref;
    if (i == 0) row_off[NND] = NEP;
}

// ---------------- CSR fill (2 edges/thread; cursor pre-seeded with row_off) ----------------
__global__ void k_fill(const void* __restrict__ ei, const int* __restrict__ flag,
                       int* __restrict__ cursor, int* __restrict__ col) {
    int e0 = (blockIdx.x * 256 + threadIdx.x) * 2;
    if (e0 >= NEP) return;
    const int is64 = *flag;
    int s0, d0, s1, d1;
    load_edge(ei, is64, e0, s0, d0);
    load_edge(ei, is64, e0 + 1, s1, d1);
    col[atomicAdd(&cursor[d0], 1)] = s0;
    col[atomicAdd(&cursor[d1], 1)] = s1;
}

// ---------------- Wc = W1 @ W2 fused with split/transpose; bc = b1 @ W2 ----------------
__global__ void k_wcombsplit(const float* __restrict__ W1, const float* __restrict__ W2,
                             const float* __restrict__ b1, unsigned short* __restrict__ wtCh,
                             unsigned short* __restrict__ wtCl, float* __restrict__ bc) {
    const int j = threadIdx.x;  // 0..127 (N dim)
    const int i = blockIdx.x;   // 0..127 K rows; 128 -> bias
    const float* rowv = (i < 128) ? (W1 + (size_t)i * 256) : b1;
    float acc = 0.f;
    for (int k = 0; k < 256; ++k) acc = fmaf(rowv[k], W2[(size_t)k * 128 + j], acc);
    if (i < 128) {
        uint32_t hi = f32_to_bf16_rne(acc);
        float resid = acc - bf16bits_to_f32(hi);
        uint32_t lo = f32_to_bf16_rne(resid);
        wtCh[(size_t)j * 128 + i] = (unsigned short)hi;  // transposed planar
        wtCl[(size_t)j * 128 + i] = (unsigned short)lo;
    } else {
        bc[j] = acc;
    }
}

// ---------------- W prep: transpose + split into planar bf16 hi/lo ----------------
__global__ void k_wprep(const float* __restrict__ W, unsigned short* __restrict__ wth,
                        unsigned short* __restrict__ wtl, int K, int N) {
    int i = blockIdx.x * 256 + threadIdx.x;
    if (i >= K * N) return;
    int k = i / N, n = i % N;
    float x = W[i];
    uint32_t hi = f32_to_bf16_rne(x);
    float resid = x - bf16bits_to_f32(hi);
    uint32_t lo = f32_to_bf16_rne(resid);
    wth[(size_t)n * K + k] = (unsigned short)hi;
    wtl[(size_t)n * K + k] = (unsigned short)lo;
}

// ---------------- aggregation (proven structure: block per node) ----------------
// out[n] = dinv[n] * sum_{src in N(n)} dinv[src] * in[src]  (+bias, relu)
template <int C, bool BIAS, bool RELU, bool OUT_SPLIT>
__global__ __launch_bounds__(C) void k_agg(const float* __restrict__ in, float* __restrict__ out,
                      const int* __restrict__ row_off, const int* __restrict__ col,
                      const float* __restrict__ dinv, const float* __restrict__ bias,
                      unsigned short* __restrict__ outh, unsigned short* __restrict__ outl) {
    constexpr int LPG = C / 4;  // lanes per group (float4 each)
    constexpr int NG = 4;       // edge groups
    constexpr int MAXE = 256;   // staged edges per chunk
    __shared__ int sidx[MAXE];
    __shared__ float snrm[MAXE];
    __shared__ float4 red[NG][LPG];

    const int n = blockIdx.x;
    const int t = threadIdx.x;
    const int g = t / LPG;
    const int l = t % LPG;
    const int s = row_off[n], e = row_off[n + 1];
    const float4* __restrict__ in4 = (const float4*)in;

    float4 a0 = make_float4(0.f, 0.f, 0.f, 0.f);
    float4 a1 = make_float4(0.f, 0.f, 0.f, 0.f);
    float4 a2 = make_float4(0.f, 0.f, 0.f, 0.f);
    float4 a3 = make_float4(0.f, 0.f, 0.f, 0.f);

    for (int base = s; base < e; base += MAXE) {
        const int cnt = min(e - base, MAXE);
        for (int i = t; i < cnt; i += C) {
            int c = col[base + i];
            sidx[i] = c;
            snrm[i] = dinv[c];
        }
        __syncthreads();

        int k = g;
        for (; k + 3 * NG < cnt; k += 4 * NG) {
            int s0 = sidx[k];
            int s1 = sidx[k + NG];
            int s2 = sidx[k + 2 * NG];
            int s3 = sidx[k + 3 * NG];
            float d0 = snrm[k];
            float d1 = snrm[k + NG];
            float d2 = snrm[k + 2 * NG];
            float d3 = snrm[k + 3 * NG];
            float4 v0 = in4[(size_t)s0 * LPG + l];
            float4 v1 = in4[(size_t)s1 * LPG + l];
            float4 v2 = in4[(size_t)s2 * LPG + l];
            float4 v3 = in4[(size_t)s3 * LPG + l];
            a0.x = fmaf(d0, v0.x, a0.x); a0.y = fmaf(d0, v0.y, a0.y);
            a0.z = fmaf(d0, v0.z, a0.z); a0.w = fmaf(d0, v0.w, a0.w);
            a1.x = fmaf(d1, v1.x, a1.x); a1.y = fmaf(d1, v1.y, a1.y);
            a1.z = fmaf(d1, v1.z, a1.z); a1.w = fmaf(d1, v1.w, a1.w);
            a2.x = fmaf(d2, v2.x, a2.x); a2.y = fmaf(d2, v2.y, a2.y);
            a2.z = fmaf(d2, v2.z, a2.z); a2.w = fmaf(d2, v2.w, a2.w);
            a3.x = fmaf(d3, v3.x, a3.x); a3.y = fmaf(d3, v3.y, a3.y);
            a3.z = fmaf(d3, v3.z, a3.z); a3.w = fmaf(d3, v3.w, a3.w);
        }
        for (; k < cnt; k += NG) {
            int s0 = sidx[k];
            float d0 = snrm[k];
            float4 v0 = in4[(size_t)s0 * LPG + l];
            a0.x = fmaf(d0, v0.x, a0.x); a0.y = fmaf(d0, v0.y, a0.y);
            a0.z = fmaf(d0, v0.z, a0.z); a0.w = fmaf(d0, v0.w, a0.w);
        }
        __syncthreads();  // protect sidx/snrm before next chunk
    }

    a0.x += a1.x + a2.x + a3.x;
    a0.y += a1.y + a2.y + a3.y;
    a0.z += a1.z + a2.z + a3.z;
    a0.w += a1.w + a2.w + a3.w;
    red[g][l] = a0;
    __syncthreads();
    if (g == 0) {
        float4 r = red[0][l];
        float4 r1 = red[1][l];
        float4 r2 = red[2][l];
        float4 r3 = red[3][l];
        r.x += r1.x + r2.x + r3.x;
        r.y += r1.y + r2.y + r3.y;
        r.z += r1.z + r2.z + r3.z;
        r.w += r1.w + r2.w + r3.w;
        float dn = dinv[n];
        r.x *= dn; r.y *= dn; r.z *= dn; r.w *= dn;
        if constexpr (BIAS) {
            float4 bv = ((const float4*)bias)[l];
            r.x += bv.x; r.y += bv.y; r.z += bv.z; r.w += bv.w;
        }
        if constexpr (RELU) {
            r.x = fmaxf(r.x, 0.f); r.y = fmaxf(r.y, 0.f);
            r.z = fmaxf(r.z, 0.f); r.w = fmaxf(r.w, 0.f);
        }
        if constexpr (OUT_SPLIT) {
            uint32_t h0 = f32_to_bf16_rne(r.x), h1 = f32_to_bf16_rne(r.y);
            uint32_t h2 = f32_to_bf16_rne(r.z), h3 = f32_to_bf16_rne(r.w);
            uint32_t l0 = f32_to_bf16_rne(r.x - bf16bits_to_f32(h0));
            uint32_t l1 = f32_to_bf16_rne(r.y - bf16bits_to_f32(h1));
            uint32_t l2 = f32_to_bf16_rne(r.z - bf16bits_to_f32(h2));
            uint32_t l3 = f32_to_bf16_rne(r.w - bf16bits_to_f32(h3));
            uint2 oh = make_uint2(h0 | (h1 << 16), h2 | (h3 << 16));
            uint2 ol = make_uint2(l0 | (l1 << 16), l2 | (l3 << 16));
            *(uint2*)(outh + (size_t)n * C + l * 4) = oh;
            *(uint2*)(outl + (size_t)n * C + l * 4) = ol;
        } else {
            ((float4*)out)[(size_t)n * LPG + l] = r;
        }
    }
}

// ---------------- MFMA split-bf16 GEMM, LDS-staged act, W-slice in registers ----
template <int K, int N, int WN, int WM, bool BIAS, bool OUT_SPLIT>
__global__ __launch_bounds__(WN * WM * 64, 3) void k_mgemm(
    const unsigned short* __restrict__ acth, const unsigned short* __restrict__ actl,
    const unsigned short* __restrict__ wth, const unsigned short* __restrict__ wtl,
    const float* __restrict__ bias, float* __restrict__ outf,
    unsigned short* __restrict__ outh, unsigned short* __restrict__ outl, int nrows)
{
    constexpr int BM = 64;               // rows per block
    constexpr int BK = 128;              // LDS K-chunk
    constexpr int NCH = K / BK;          // chunks
    constexpr int KC = BK / 32;          // mfma K-steps per chunk
    constexpr int KP = BK + 8;           // padded LDS row (shorts)
    constexpr int NTW = N / (WN * 16);   // n-tiles per wave
    constexpr int RT = 4 / WM;           // 16-row subtiles per wave
    constexpr int NTHR = WN * WM * 64;
    constexpr int CHUNKS = BM * BK / 8;  // 16B chunks per plane

    __shared__ unsigned short sh[2][BM][KP];

    const int tid = threadIdx.x;
    const int lane = tid & 63;
    const int wave = tid >> 6;
    const int wn = wave % WN;
    const int wm = wave / WN;
    const int l15 = lane & 15;
    const int lq = lane >> 4;  // 0..3
    const int r0 = blockIdx.x * BM;
    const int ncol0 = wn * NTW * 16;

    v8s wh[NTW][K / 32], wl[NTW][K / 32];
#pragma unroll
    for (int nt = 0; nt < NTW; ++nt) {
        const size_t nrow = (size_t)(ncol0 + nt * 16 + l15) * K;
#pragma unroll
        for (int kk = 0; kk < K / 32; ++kk) {
            wh[nt][kk] = *(const v8s*)(wth + nrow + kk * 32 + lq * 8);
            wl[nt][kk] = *(const v8s*)(wtl + nrow + kk * 32 + lq * 8);
        }
    }

    v4f acc[RT][NTW];
#pragma unroll
    for (int rt = 0; rt < RT; ++rt)
#pragma unroll
        for (int nt = 0; nt < NTW; ++nt) acc[rt][nt] = (v4f){0.f, 0.f, 0.f, 0.f};

#pragma unroll
    for (int ch = 0; ch < NCH; ++ch) {
        if (ch) __syncthreads();
        for (int i = tid; i < 2 * CHUNKS; i += NTHR) {
            const int plane = i >= CHUNKS;
            const int j = plane ? i - CHUNKS : i;
            const int r = j / (BK / 8);
            const int c = (j % (BK / 8)) * 8;
            int gr = r0 + r;
            if (gr >= nrows) gr = nrows - 1;
            const unsigned short* src = (plane ? actl : acth) + (size_t)gr * K + ch * BK + c;
            *(v8s*)(&sh[plane][r][c]) = *(const v8s*)src;
        }
        __syncthreads();

#pragma unroll
        for (int kc = 0; kc < KC; ++kc) {
#pragma unroll
            for (int rt = 0; rt < RT; ++rt) {
                const int row = (wm * RT + rt) * 16 + l15;
                const v8s ah = *(const v8s*)(&sh[0][row][kc * 32 + lq * 8]);
                const v8s al = *(const v8s*)(&sh[1][row][kc * 32 + lq * 8]);
                const int kk = ch * KC + kc;
#pragma unroll
                for (int nt = 0; nt < NTW; ++nt) {
                    acc[rt][nt] = __builtin_amdgcn_mfma_f32_16x16x32_bf16(wh[nt][kk], ah, acc[rt][nt], 0, 0, 0);
                    acc[rt][nt] = __builtin_amdgcn_mfma_f32_16x16x32_bf16(wh[nt][kk], al, acc[rt][nt], 0, 0, 0);
                    acc[rt][nt] = __builtin_amdgcn_mfma_f32_16x16x32_bf16(wl[nt][kk], ah, acc[rt][nt], 0, 0, 0);
                }
            }
        }
    }

#pragma unroll
    for (int rt = 0; rt < RT; ++rt) {
        const int m = r0 + (wm * RT + rt) * 16 + l15;
        if (m >= nrows) continue;
#pragma unroll
        for (int nt = 0; nt < NTW; ++nt) {
            const int nc = ncol0 + nt * 16 + lq * 4;
            v4f v = acc[rt][nt];
            if constexpr (BIAS) {
                float4 bv = *(const float4*)(bias + nc);
                v[0] += bv.x; v[1] += bv.y; v[2] += bv.z; v[3] += bv.w;
            }
            if constexpr (OUT_SPLIT) {
                uint32_t h0 = f32_to_bf16_rne(v[0]), h1 = f32_to_bf16_rne(v[1]);
                uint32_t h2 = f32_to_bf16_rne(v[2]), h3 = f32_to_bf16_rne(v[3]);
                uint32_t l0 = f32_to_bf16_rne(v[0] - bf16bits_to_f32(h0));
                uint32_t l1 = f32_to_bf16_rne(v[1] - bf16bits_to_f32(h1));
                uint32_t l2 = f32_to_bf16_rne(v[2] - bf16bits_to_f32(h2));
                uint32_t l3 = f32_to_bf16_rne(v[3] - bf16bits_to_f32(h3));
                *(uint2*)(outh + (size_t)m * N + nc) = make_uint2(h0 | (h1 << 16), h2 | (h3 << 16));
                *(uint2*)(outl + (size_t)m * N + nc) = make_uint2(l0 | (l1 << 16), l2 | (l3 << 16));
            } else {
                *(float4*)(outf + (size_t)m * N + nc) = make_float4(v[0], v[1], v[2], v[3]);
            }
        }
    }
}

// ---------------- host ----------------
extern "C" void kernel_launch(void* const* d_in, const int* in_sizes, int n_in,
                              void* d_out, int out_size, void* d_ws, size_t ws_size,
                              hipStream_t stream) {
    const float* x = (const float*)d_in[0];
    const void* ei = d_in[1];
    const float* W1 = (const float*)d_in[2];
    const float* b1 = (const float*)d_in[3];
    const float* W2 = (const float*)d_in[4];
    const float* b2 = (const float*)d_in[5];
    const float* W3 = (const float*)d_in[6];
    const float* b3 = (const float*)d_in[7];
    float* out = (float*)d_out;

    char* ws = (char*)d_ws;
    size_t off = 0;
    auto alloc = [&](size_t bytes) -> void* {
        void* p = ws + off;
        off = (off + bytes + 255) & ~(size_t)255;
        return p;
    };

    int* flag = (int*)alloc(sizeof(int));
    int* deg = (int*)alloc((size_t)NND * 4);
    int* cursor = (int*)alloc((size_t)NND * 4);
    int* row_off = (int*)alloc((size_t)(NND + 1) * 4);
    int* bsum = (int*)alloc(512);
    float* dinv = (float*)alloc((size_t)NND * 4);
    int* col = (int*)alloc((size_t)NEP * 4);
    float* bc = (float*)alloc((size_t)128 * 4);
    unsigned short* wtCh = (unsigned short*)alloc((size_t)128 * 128 * 2);
    unsigned short* wtCl = (unsigned short*)alloc((size_t)128 * 128 * 2);
    unsigned short* wt3h = (unsigned short*)alloc((size_t)128 * 64 * 2);
    unsigned short* wt3l = (unsigned short*)alloc((size_t)128 * 64 * 2);
    unsigned short* AXh = (unsigned short*)alloc((size_t)NND * 128 * 2 * 2);
    unsigned short* AXl = AXh + (size_t)NND * 128;
    float* H2 = (float*)alloc((size_t)NND * 128 * 4);
    unsigned short* A2h = AXh;  // AX dead after gemmC -> reuse for A2
    unsigned short* A2l = AXl;
    float* H3 = H2;             // H2 dead after agg2 -> reuse for H3

    hipMemsetAsync(deg, 0, (size_t)NND * 4, stream);

    k_detect<<<1, 256, 0, stream>>>((const long long*)ei, flag);

    const int gP = (NEP / 2 + 255) / 256;  // 2 edges per thread
    const int gN = (NND + 255) / 256;
    k_deg<<<gP, 256, 0, stream>>>(ei, flag, deg);

    const int NB = (NND + 1023) / 1024;  // 98
    k_scan1<<<NB, 1024, 0, stream>>>(deg, row_off, bsum, dinv);
    k_scan23<<<gN, 256, 0, stream>>>(row_off, bsum);

    // seed cursor with row_off (d2d copy; then fill needs ONE atomic per edge)
    hipMemcpyAsync(cursor, row_off, (size_t)NND * 4, hipMemcpyDeviceToDevice, stream);
    k_fill<<<gP, 256, 0, stream>>>(ei, flag, cursor, col);

    // fused W: Wc = W1@W2 -> split/transposed directly; bc = b1@W2
    k_wcombsplit<<<129, 128, 0, stream>>>(W1, W2, b1, wtCh, wtCl, bc);
    k_wprep<<<(128 * 64 + 255) / 256, 256, 0, stream>>>(W3, wt3h, wt3l, 128, 64);

    const int gT = (NND + 63) / 64;  // 1563 row-tiles

    // L1+L2 dense fused: AX = Ahat @ X ; H2 = AX @ Wc + bc
    k_agg<128, false, false, true><<<NND, 128, 0, stream>>>(x, nullptr, row_off, col, dinv, nullptr, AXh, AXl);
    k_mgemm<128, 128, 8, 1, true, false><<<gT, 512, 0, stream>>>(AXh, AXl, wtCh, wtCl, bc, H2, nullptr, nullptr, NND);

    // L2 agg: A2 = relu(Ahat @ H2 + b2)
    k_agg<128, true, true, true><<<NND, 128, 0, stream>>>(H2, nullptr, row_off, col, dinv, b2, A2h, A2l);

    // L3: H3 = A2 @ W3 ; out = Ahat @ H3 + b3
    k_mgemm<128, 64, 4, 2, false, false><<<gT, 512, 0, stream>>>(A2h, A2l, wt3h, wt3l, nullptr, H3, nullptr, nullptr, NND);
    k_agg<64, true, false, false><<<NND, 64, 0, stream>>>(H3, out, row_off, col, dinv, b3, nullptr, nullptr);
}

// Round 11
// 443.972 us; speedup vs baseline: 1.2602x; 1.2602x over previous
//
#include <hip/hip_runtime.h>
#include <cstddef>
#include <cstdint>

#define NND 100000
#define NED 1600000
#define NEP (NED + NND)
#define NPB 256                          // nodes per bucket (shift by 8)
#define NBK ((NND + NPB - 1) / NPB)      // 391 buckets
#define ECH 2048                         // edges per chunk-block

typedef short v8s __attribute__((ext_vector_type(8)));
typedef float v4f __attribute__((ext_vector_type(4)));

// ---------------- bf16 split helpers ----------------
__device__ __forceinline__ uint32_t f32_to_bf16_rne(float x) {
    uint32_t u = __builtin_bit_cast(uint32_t, x);
    return (u + 0x7fffu + ((u >> 16) & 1u)) >> 16;
}
__device__ __forceinline__ float bf16bits_to_f32(uint32_t b) {
    return __builtin_bit_cast(float, b << 16);
}

// ---------------- edge dtype detection ----------------
__global__ void k_detect(const long long* __restrict__ ei, int* __restrict__ flag) {
    __shared__ int ok;
    if (threadIdx.x == 0) ok = 1;
    __syncthreads();
    for (int i = threadIdx.x; i < 2048; i += blockDim.x) {
        long long v = ei[i];
        if (v < 0 || v >= NND) ok = 0;
    }
    __syncthreads();
    if (threadIdx.x == 0) *flag = ok;
}

__device__ __forceinline__ void load_edge(const void* ei, int is64, int e, int& src, int& dst) {
    if (e >= NED) { src = dst = e - NED; return; }  // self-loop
    if (is64) {
        const long long* p = (const long long*)ei;
        src = (int)p[e];
        dst = (int)p[NED + e];
    } else {
        const int* p = (const int*)ei;
        src = p[e];
        dst = p[NED + e];
    }
}

// ---------------- phase A: per-bucket edge counts (LDS histogram) ----------------
__global__ __launch_bounds__(256) void k_bcount(const void* __restrict__ ei,
                                                const int* __restrict__ flag,
                                                int* __restrict__ bcnt) {
    __shared__ int cnt[NBK];
    const int t = threadIdx.x;
    for (int j = t; j < NBK; j += 256) cnt[j] = 0;
    __syncthreads();
    const int is64 = *flag;
    const int e0 = blockIdx.x * ECH;
#pragma unroll
    for (int i = 0; i < 8; ++i) {
        int e = e0 + t + i * 256;
        if (e < NEP) {
            int s, d;
            load_edge(ei, is64, e, s, d);
            atomicAdd(&cnt[d >> 8], 1);
        }
    }
    __syncthreads();
    for (int j = t; j < NBK; j += 256)
        if (cnt[j]) atomicAdd(&bcnt[j], cnt[j]);
}

// ---------------- bucket scan: boff (exclusive) + seed bcur ----------------
__global__ __launch_bounds__(512) void k_bscan(const int* __restrict__ bcnt,
                                               int* __restrict__ boff,
                                               int* __restrict__ bcur) {
    __shared__ int sh[512];
    const int t = threadIdx.x;
    int v = (t < NBK) ? bcnt[t] : 0;
    sh[t] = v;
    __syncthreads();
    for (int off = 1; off < 512; off <<= 1) {
        int u = 0;
        if (t >= off) u = sh[t - off];
        __syncthreads();
        sh[t] += u;
        __syncthreads();
    }
    if (t < NBK) {
        int e = sh[t] - v;  // exclusive
        boff[t] = e;
        bcur[t] = e;
    }
    if (t == NBK) boff[NBK] = NEP;
}

// ---------------- phase B: scatter (src,dst) pairs into bucket regions ----------------
// Block reserves a contiguous range per bucket -> consecutive 8B writes fill lines.
__global__ __launch_bounds__(256) void k_bscatter(const void* __restrict__ ei,
                                                  const int* __restrict__ flag,
                                                  int* __restrict__ bcur,
                                                  uint2* __restrict__ pairs) {
    __shared__ int cnt[NBK];
    __shared__ int res[NBK];
    const int t = threadIdx.x;
    for (int j = t; j < NBK; j += 256) cnt[j] = 0;
    __syncthreads();
    const int is64 = *flag;
    const int e0 = blockIdx.x * ECH;
    int se[8], de[8], rk[8];
#pragma unroll
    for (int i = 0; i < 8; ++i) {
        int e = e0 + t + i * 256;
        if (e < NEP) {
            load_edge(ei, is64, e, se[i], de[i]);
            rk[i] = atomicAdd(&cnt[de[i] >> 8], 1);
        } else {
            de[i] = -1;
        }
    }
    __syncthreads();
    for (int j = t; j < NBK; j += 256) {
        int c = cnt[j];
        if (c) res[j] = atomicAdd(&bcur[j], c);
    }
    __syncthreads();
#pragma unroll
    for (int i = 0; i < 8; ++i) {
        if (de[i] >= 0) {
            int pos = res[de[i] >> 8] + rk[i];
            pairs[pos] = make_uint2((unsigned)se[i], (unsigned)de[i]);
        }
    }
}

// ---------------- phase C: per-bucket CSR build (no global atomics) ----------------
__global__ __launch_bounds__(256) void k_bcsr(const uint2* __restrict__ pairs,
                                              const int* __restrict__ boff,
                                              int* __restrict__ row_off,
                                              float* __restrict__ dinv,
                                              int* __restrict__ col) {
    __shared__ int deg[NPB];
    __shared__ int off[NPB];
    __shared__ int cur[NPB];
    const int b = blockIdx.x;
    const int t = threadIdx.x;
    const int node0 = b * NPB;
    const int es = boff[b], ee = boff[b + 1];

    deg[t] = 0;
    __syncthreads();
    for (int e = es + t; e < ee; e += 256) {
        uint2 p = pairs[e];
        atomicAdd(&deg[p.y - node0], 1);
    }
    __syncthreads();
    // exclusive scan of deg
    int v = deg[t];
    off[t] = v;
    __syncthreads();
    for (int o = 1; o < 256; o <<= 1) {
        int u = 0;
        if (t >= o) u = off[t - o];
        __syncthreads();
        off[t] += u;
        __syncthreads();
    }
    const int excl = off[t] - v;
    const int node = node0 + t;
    if (node <= NND) row_off[node] = es + excl;  // node==NND lands here (b=390,t=160)
    if (node < NND) {
        int dd = v < 1 ? 1 : v;
        dinv[node] = 1.0f / sqrtf((float)dd);
    }
    cur[t] = es + excl;
    __syncthreads();
    for (int e = es + t; e < ee; e += 256) {
        uint2 p = pairs[e];
        int pos = atomicAdd(&cur[p.y - node0], 1);
        col[pos] = (int)p.x;
    }
}

// ---------------- Wc = W1 @ W2 fused with split/transpose; bc = b1 @ W2 ----------------
__global__ void k_wcombsplit(const float* __restrict__ W1, const float* __restrict__ W2,
                             const float* __restrict__ b1, unsigned short* __restrict__ wtCh,
                             unsigned short* __restrict__ wtCl, float* __restrict__ bc) {
    const int j = threadIdx.x;  // 0..127 (N dim)
    const int i = blockIdx.x;   // 0..127 K rows; 128 -> bias
    const float* rowv = (i < 128) ? (W1 + (size_t)i * 256) : b1;
    float acc = 0.f;
    for (int k = 0; k < 256; ++k) acc = fmaf(rowv[k], W2[(size_t)k * 128 + j], acc);
    if (i < 128) {
        uint32_t hi = f32_to_bf16_rne(acc);
        float resid = acc - bf16bits_to_f32(hi);
        uint32_t lo = f32_to_bf16_rne(resid);
        wtCh[(size_t)j * 128 + i] = (unsigned short)hi;  // transposed planar
        wtCl[(size_t)j * 128 + i] = (unsigned short)lo;
    } else {
        bc[j] = acc;
    }
}

// ---------------- W prep: transpose + split into planar bf16 hi/lo ----------------
__global__ void k_wprep(const float* __restrict__ W, unsigned short* __restrict__ wth,
                        unsigned short* __restrict__ wtl, int K, int N) {
    int i = blockIdx.x * 256 + threadIdx.x;
    if (i >= K * N) return;
    int k = i / N, n = i % N;
    float x = W[i];
    uint32_t hi = f32_to_bf16_rne(x);
    float resid = x - bf16bits_to_f32(hi);
    uint32_t lo = f32_to_bf16_rne(resid);
    wth[(size_t)n * K + k] = (unsigned short)hi;
    wtl[(size_t)n * K + k] = (unsigned short)lo;
}

// ---------------- aggregation (proven structure: block per node) ----------------
template <int C, bool BIAS, bool RELU, bool OUT_SPLIT>
__global__ __launch_bounds__(C) void k_agg(const float* __restrict__ in, float* __restrict__ out,
                      const int* __restrict__ row_off, const int* __restrict__ col,
                      const float* __restrict__ dinv, const float* __restrict__ bias,
                      unsigned short* __restrict__ outh, unsigned short* __restrict__ outl) {
    constexpr int LPG = C / 4;  // lanes per group (float4 each)
    constexpr int NG = 4;       // edge groups
    constexpr int MAXE = 256;   // staged edges per chunk
    __shared__ int sidx[MAXE];
    __shared__ float snrm[MAXE];
    __shared__ float4 red[NG][LPG];

    const int n = blockIdx.x;
    const int t = threadIdx.x;
    const int g = t / LPG;
    const int l = t % LPG;
    const int s = row_off[n], e = row_off[n + 1];
    const float4* __restrict__ in4 = (const float4*)in;

    float4 a0 = make_float4(0.f, 0.f, 0.f, 0.f);
    float4 a1 = make_float4(0.f, 0.f, 0.f, 0.f);
    float4 a2 = make_float4(0.f, 0.f, 0.f, 0.f);
    float4 a3 = make_float4(0.f, 0.f, 0.f, 0.f);

    for (int base = s; base < e; base += MAXE) {
        const int cnt = min(e - base, MAXE);
        for (int i = t; i < cnt; i += C) {
            int c = col[base + i];
            sidx[i] = c;
            snrm[i] = dinv[c];
        }
        __syncthreads();

        int k = g;
        for (; k + 3 * NG < cnt; k += 4 * NG) {
            int s0 = sidx[k];
            int s1 = sidx[k + NG];
            int s2 = sidx[k + 2 * NG];
            int s3 = sidx[k + 3 * NG];
            float d0 = snrm[k];
            float d1 = snrm[k + NG];
            float d2 = snrm[k + 2 * NG];
            float d3 = snrm[k + 3 * NG];
            float4 v0 = in4[(size_t)s0 * LPG + l];
            float4 v1 = in4[(size_t)s1 * LPG + l];
            float4 v2 = in4[(size_t)s2 * LPG + l];
            float4 v3 = in4[(size_t)s3 * LPG + l];
            a0.x = fmaf(d0, v0.x, a0.x); a0.y = fmaf(d0, v0.y, a0.y);
            a0.z = fmaf(d0, v0.z, a0.z); a0.w = fmaf(d0, v0.w, a0.w);
            a1.x = fmaf(d1, v1.x, a1.x); a1.y = fmaf(d1, v1.y, a1.y);
            a1.z = fmaf(d1, v1.z, a1.z); a1.w = fmaf(d1, v1.w, a1.w);
            a2.x = fmaf(d2, v2.x, a2.x); a2.y = fmaf(d2, v2.y, a2.y);
            a2.z = fmaf(d2, v2.z, a2.z); a2.w = fmaf(d2, v2.w, a2.w);
            a3.x = fmaf(d3, v3.x, a3.x); a3.y = fmaf(d3, v3.y, a3.y);
            a3.z = fmaf(d3, v3.z, a3.z); a3.w = fmaf(d3, v3.w, a3.w);
        }
        for (; k < cnt; k += NG) {
            int s0 = sidx[k];
            float d0 = snrm[k];
            float4 v0 = in4[(size_t)s0 * LPG + l];
            a0.x = fmaf(d0, v0.x, a0.x); a0.y = fmaf(d0, v0.y, a0.y);
            a0.z = fmaf(d0, v0.z, a0.z); a0.w = fmaf(d0, v0.w, a0.w);
        }
        __syncthreads();  // protect sidx/snrm before next chunk
    }

    a0.x += a1.x + a2.x + a3.x;
    a0.y += a1.y + a2.y + a3.y;
    a0.z += a1.z + a2.z + a3.z;
    a0.w += a1.w + a2.w + a3.w;
    red[g][l] = a0;
    __syncthreads();
    if (g == 0) {
        float4 r = red[0][l];
        float4 r1 = red[1][l];
        float4 r2 = red[2][l];
        float4 r3 = red[3][l];
        r.x += r1.x + r2.x + r3.x;
        r.y += r1.y + r2.y + r3.y;
        r.z += r1.z + r2.z + r3.z;
        r.w += r1.w + r2.w + r3.w;
        float dn = dinv[n];
        r.x *= dn; r.y *= dn; r.z *= dn; r.w *= dn;
        if constexpr (BIAS) {
            float4 bv = ((const float4*)bias)[l];
            r.x += bv.x; r.y += bv.y; r.z += bv.z; r.w += bv.w;
        }
        if constexpr (RELU) {
            r.x = fmaxf(r.x, 0.f); r.y = fmaxf(r.y, 0.f);
            r.z = fmaxf(r.z, 0.f); r.w = fmaxf(r.w, 0.f);
        }
        if constexpr (OUT_SPLIT) {
            uint32_t h0 = f32_to_bf16_rne(r.x), h1 = f32_to_bf16_rne(r.y);
            uint32_t h2 = f32_to_bf16_rne(r.z), h3 = f32_to_bf16_rne(r.w);
            uint32_t l0 = f32_to_bf16_rne(r.x - bf16bits_to_f32(h0));
            uint32_t l1 = f32_to_bf16_rne(r.y - bf16bits_to_f32(h1));
            uint32_t l2 = f32_to_bf16_rne(r.z - bf16bits_to_f32(h2));
            uint32_t l3 = f32_to_bf16_rne(r.w - bf16bits_to_f32(h3));
            uint2 oh = make_uint2(h0 | (h1 << 16), h2 | (h3 << 16));
            uint2 ol = make_uint2(l0 | (l1 << 16), l2 | (l3 << 16));
            *(uint2*)(outh + (size_t)n * C + l * 4) = oh;
            *(uint2*)(outl + (size_t)n * C + l * 4) = ol;
        } else {
            ((float4*)out)[(size_t)n * LPG + l] = r;
        }
    }
}

// ---------------- MFMA split-bf16 GEMM, LDS-staged act, W-slice in registers ----
template <int K, int N, int WN, int WM, bool BIAS, bool OUT_SPLIT>
__global__ __launch_bounds__(WN * WM * 64, 3) void k_mgemm(
    const unsigned short* __restrict__ acth, const unsigned short* __restrict__ actl,
    const unsigned short* __restrict__ wth, const unsigned short* __restrict__ wtl,
    const float* __restrict__ bias, float* __restrict__ outf,
    unsigned short* __restrict__ outh, unsigned short* __restrict__ outl, int nrows)
{
    constexpr int BM = 64;               // rows per block
    constexpr int BK = 128;              // LDS K-chunk
    constexpr int NCH = K / BK;          // chunks
    constexpr int KC = BK / 32;          // mfma K-steps per chunk
    constexpr int KP = BK + 8;           // padded LDS row (shorts)
    constexpr int NTW = N / (WN * 16);   // n-tiles per wave
    constexpr int RT = 4 / WM;           // 16-row subtiles per wave
    constexpr int NTHR = WN * WM * 64;
    constexpr int CHUNKS = BM * BK / 8;  // 16B chunks per plane

    __shared__ unsigned short sh[2][BM][KP];

    const int tid = threadIdx.x;
    const int lane = tid & 63;
    const int wave = tid >> 6;
    const int wn = wave % WN;
    const int wm = wave / WN;
    const int l15 = lane & 15;
    const int lq = lane >> 4;  // 0..3
    const int r0 = blockIdx.x * BM;
    const int ncol0 = wn * NTW * 16;

    v8s wh[NTW][K / 32], wl[NTW][K / 32];
#pragma unroll
    for (int nt = 0; nt < NTW; ++nt) {
        const size_t nrow = (size_t)(ncol0 + nt * 16 + l15) * K;
#pragma unroll
        for (int kk = 0; kk < K / 32; ++kk) {
            wh[nt][kk] = *(const v8s*)(wth + nrow + kk * 32 + lq * 8);
            wl[nt][kk] = *(const v8s*)(wtl + nrow + kk * 32 + lq * 8);
        }
    }

    v4f acc[RT][NTW];
#pragma unroll
    for (int rt = 0; rt < RT; ++rt)
#pragma unroll
        for (int nt = 0; nt < NTW; ++nt) acc[rt][nt] = (v4f){0.f, 0.f, 0.f, 0.f};

#pragma unroll
    for (int ch = 0; ch < NCH; ++ch) {
        if (ch) __syncthreads();
        for (int i = tid; i < 2 * CHUNKS; i += NTHR) {
            const int plane = i >= CHUNKS;
            const int j = plane ? i - CHUNKS : i;
            const int r = j / (BK / 8);
            const int c = (j % (BK / 8)) * 8;
            int gr = r0 + r;
            if (gr >= nrows) gr = nrows - 1;
            const unsigned short* src = (plane ? actl : acth) + (size_t)gr * K + ch * BK + c;
            *(v8s*)(&sh[plane][r][c]) = *(const v8s*)src;
        }
        __syncthreads();

#pragma unroll
        for (int kc = 0; kc < KC; ++kc) {
#pragma unroll
            for (int rt = 0; rt < RT; ++rt) {
                const int row = (wm * RT + rt) * 16 + l15;
                const v8s ah = *(const v8s*)(&sh[0][row][kc * 32 + lq * 8]);
                const v8s al = *(const v8s*)(&sh[1][row][kc * 32 + lq * 8]);
                const int kk = ch * KC + kc;
#pragma unroll
                for (int nt = 0; nt < NTW; ++nt) {
                    acc[rt][nt] = __builtin_amdgcn_mfma_f32_16x16x32_bf16(wh[nt][kk], ah, acc[rt][nt], 0, 0, 0);
                    acc[rt][nt] = __builtin_amdgcn_mfma_f32_16x16x32_bf16(wh[nt][kk], al, acc[rt][nt], 0, 0, 0);
                    acc[rt][nt] = __builtin_amdgcn_mfma_f32_16x16x32_bf16(wl[nt][kk], ah, acc[rt][nt], 0, 0, 0);
                }
            }
        }
    }

#pragma unroll
    for (int rt = 0; rt < RT; ++rt) {
        const int m = r0 + (wm * RT + rt) * 16 + l15;
        if (m >= nrows) continue;
#pragma unroll
        for (int nt = 0; nt < NTW; ++nt) {
            const int nc = ncol0 + nt * 16 + lq * 4;
            v4f v = acc[rt][nt];
            if constexpr (BIAS) {
                float4 bv = *(const float4*)(bias + nc);
                v[0] += bv.x; v[1] += bv.y; v[2] += bv.z; v[3] += bv.w;
            }
            if constexpr (OUT_SPLIT) {
                uint32_t h0 = f32_to_bf16_rne(v[0]), h1 = f32_to_bf16_rne(v[1]);
                uint32_t h2 = f32_to_bf16_rne(v[2]), h3 = f32_to_bf16_rne(v[3]);
                uint32_t l0 = f32_to_bf16_rne(v[0] - bf16bits_to_f32(h0));
                uint32_t l1 = f32_to_bf16_rne(v[1] - bf16bits_to_f32(h1));
                uint32_t l2 = f32_to_bf16_rne(v[2] - bf16bits_to_f32(h2));
                uint32_t l3 = f32_to_bf16_rne(v[3] - bf16bits_to_f32(h3));
                *(uint2*)(outh + (size_t)m * N + nc) = make_uint2(h0 | (h1 << 16), h2 | (h3 << 16));
                *(uint2*)(outl + (size_t)m * N + nc) = make_uint2(l0 | (l1 << 16), l2 | (l3 << 16));
            } else {
                *(float4*)(outf + (size_t)m * N + nc) = make_float4(v[0], v[1], v[2], v[3]);
            }
        }
    }
}

// ---------------- host ----------------
extern "C" void kernel_launch(void* const* d_in, const int* in_sizes, int n_in,
                              void* d_out, int out_size, void* d_ws, size_t ws_size,
                              hipStream_t stream) {
    const float* x = (const float*)d_in[0];
    const void* ei = d_in[1];
    const float* W1 = (const float*)d_in[2];
    const float* b1 = (const float*)d_in[3];
    const float* W2 = (const float*)d_in[4];
    const float* b2 = (const float*)d_in[5];
    const float* W3 = (const float*)d_in[6];
    const float* b3 = (const float*)d_in[7];
    float* out = (float*)d_out;

    char* ws = (char*)d_ws;
    size_t off = 0;
    auto alloc = [&](size_t bytes) -> void* {
        void* p = ws + off;
        off = (off + bytes + 255) & ~(size_t)255;
        return p;
    };

    int* flag = (int*)alloc(sizeof(int));
    int* bcnt = (int*)alloc((size_t)NBK * 4);
    int* boff = (int*)alloc((size_t)(NBK + 1) * 4);
    int* bcur = (int*)alloc((size_t)NBK * 4);
    int* row_off = (int*)alloc((size_t)(NND + 1) * 4);
    float* dinv = (float*)alloc((size_t)NND * 4);
    int* col = (int*)alloc((size_t)NEP * 4);
    uint2* pairs = (uint2*)alloc((size_t)NEP * 8);
    float* bc = (float*)alloc((size_t)128 * 4);
    unsigned short* wtCh = (unsigned short*)alloc((size_t)128 * 128 * 2);
    unsigned short* wtCl = (unsigned short*)alloc((size_t)128 * 128 * 2);
    unsigned short* wt3h = (unsigned short*)alloc((size_t)128 * 64 * 2);
    unsigned short* wt3l = (unsigned short*)alloc((size_t)128 * 64 * 2);
    unsigned short* AXh = (unsigned short*)alloc((size_t)NND * 128 * 2 * 2);
    unsigned short* AXl = AXh + (size_t)NND * 128;
    float* H2 = (float*)alloc((size_t)NND * 128 * 4);
    unsigned short* A2h = AXh;  // AX dead after gemmC -> reuse for A2
    unsigned short* A2l = AXl;
    float* H3 = H2;             // H2 dead after agg2 -> reuse for H3

    hipMemsetAsync(bcnt, 0, (size_t)NBK * 4, stream);

    k_detect<<<1, 256, 0, stream>>>((const long long*)ei, flag);

    const int gB = (NEP + ECH - 1) / ECH;  // 831 chunk-blocks
    k_bcount<<<gB, 256, 0, stream>>>(ei, flag, bcnt);
    k_bscan<<<1, 512, 0, stream>>>(bcnt, boff, bcur);
    k_bscatter<<<gB, 256, 0, stream>>>(ei, flag, bcur, pairs);
    k_bcsr<<<NBK, 256, 0, stream>>>(pairs, boff, row_off, dinv, col);

    // fused W: Wc = W1@W2 -> split/transposed directly; bc = b1@W2
    k_wcombsplit<<<129, 128, 0, stream>>>(W1, W2, b1, wtCh, wtCl, bc);
    k_wprep<<<(128 * 64 + 255) / 256, 256, 0, stream>>>(W3, wt3h, wt3l, 128, 64);

    const int gT = (NND + 63) / 64;  // 1563 row-tiles

    // L1+L2 dense fused: AX = Ahat @ X ; H2 = AX @ Wc + bc
    k_agg<128, false, false, true><<<NND, 128, 0, stream>>>(x, nullptr, row_off, col, dinv, nullptr, AXh, AXl);
    k_mgemm<128, 128, 8, 1, true, false><<<gT, 512, 0, stream>>>(AXh, AXl, wtCh, wtCl, bc, H2, nullptr, nullptr, NND);

    // L2 agg: A2 = relu(Ahat @ H2 + b2)
    k_agg<128, true, true, true><<<NND, 128, 0, stream>>>(H2, nullptr, row_off, col, dinv, b2, A2h, A2l);

    // L3: H3 = A2 @ W3 ; out = Ahat @ H3 + b3
    k_mgemm<128, 64, 4, 2, false, false><<<gT, 512, 0, stream>>>(A2h, A2l, wt3h, wt3l, nullptr, H3, nullptr, nullptr, NND);
    k_agg<64, true, false, false><<<NND, 64, 0, stream>>>(H3, out, row_off, col, dinv, b3, nullptr, nullptr);
}